// Round 4
// baseline (733.636 us; speedup 1.0000x reference)
//
#include <hip/hip_runtime.h>

// Seq2SeqLSTM: H=64, F=8, T=512, P=64, B=1024, fp32 in/out (verified R2/R3).
// R4: global-free K-loop. x staged in LDS in 128-step chunks (bf16); decoder
// preds buffered in LDS (aliases dead xchunk) and flushed once; 8 independent
// 3-deep MFMA chains (hi/lo weight split) with bias folded into C-init.

#define Hh 64
#define Ff 8
#define Tt 512
#define Pp 64
#define BATCH 1024
#define MB 16
#define NBLK (BATCH / MB)   // 64 blocks
#define ROWS 72             // shorts per h row: 64 + 8 pad -> 144 B stride (2-way banks, free)
#define CH 128              // x-chunk steps staged per restage
#define XR 136              // shorts per xchunk row: 16*8 + 8 pad -> 272 B (16B-aligned rows)

typedef __attribute__((ext_vector_type(8))) short short8;
typedef __attribute__((ext_vector_type(4))) short short4v;
typedef __attribute__((ext_vector_type(4))) float f32x4;

__device__ __forceinline__ short f2bf(float x) {           // fp32 -> bf16 (RNE)
    unsigned u = __float_as_uint(x);
    u += 0x7fffu + ((u >> 16) & 1u);
    return (short)(u >> 16);
}
__device__ __forceinline__ float bf2f_s(short s) {
    return __uint_as_float(((unsigned)(unsigned short)s) << 16);
}
__device__ __forceinline__ float sigf(float x)   { return __fdividef(1.f, 1.f + __expf(-x)); }
__device__ __forceinline__ float tanh_f(float x) { return 1.f - __fdividef(2.f, __expf(2.f * x) + 1.f); }

// B-fragments (weights): 4 gate tiles x 3 K-chunks, hi+lo bf16 split.
// B layout (16x16x32): lane holds B[k = kc*32 + quad*8 + j][n = lane&15].
// k 0..63 -> Whh[g][k]; k 64..71 -> Wih[g][k-64] (quad 0); else 0.
__device__ __forceinline__ void load_wfrags(
    const float* __restrict__ Whh, const float* __restrict__ Wih,
    int wv, int quad, int col, short8 whi[4][3], short8 wlo[4][3])
{
    #pragma unroll
    for (int Tg = 0; Tg < 4; ++Tg) {
        int g = Tg * 64 + wv * 16 + col;
        const float* r0 = Whh + g * 64 + quad * 8;
        const float* r1 = r0 + 32;
        #pragma unroll
        for (int j = 0; j < 8; ++j) {
            float v0 = r0[j];
            short h0 = f2bf(v0);
            whi[Tg][0][j] = h0;
            wlo[Tg][0][j] = f2bf(v0 - bf2f_s(h0));
            float v1 = r1[j];
            short h1 = f2bf(v1);
            whi[Tg][1][j] = h1;
            wlo[Tg][1][j] = f2bf(v1 - bf2f_s(h1));
            float v2 = (quad == 0) ? Wih[g * 8 + j] : 0.f;
            short h2 = f2bf(v2);
            whi[Tg][2][j] = h2;
            wlo[Tg][2][j] = f2bf(v2 - bf2f_s(h2));
        }
    }
}

// One LSTM step: 24 MFMA (8 independent 3-deep chains) + in-register cell
// update; reads h from cur, x from xrow (quad 0 only), writes h (bf16) to nxt.
__device__ __forceinline__ void lstm_step(
    const short* __restrict__ cur, short* __restrict__ nxt,
    const short* __restrict__ xrow,
    const short8 whi[4][3], const short8 wlo[4][3],
    const f32x4 biasv[4], f32x4& cst, int quad, int col, int u)
{
    // A layout (16x16x32): lane holds A[m = lane&15][k = quad*8 + j]
    const short* arow = cur + col * ROWS;
    short8 a0 = *(const short8*)(arow + quad * 8);        // k  0..31 (h)
    short8 a1 = *(const short8*)(arow + 32 + quad * 8);   // k 32..63 (h)
    short8 a2 = {0, 0, 0, 0, 0, 0, 0, 0};                 // k 64..95 (x | zeros)
    if (quad == 0) a2 = *(const short8*)(xrow + col * 8);

    f32x4 z = {0.f, 0.f, 0.f, 0.f};
    f32x4 ahi[4], alo[4];
    #pragma unroll
    for (int Tg = 0; Tg < 4; ++Tg)
        ahi[Tg] = __builtin_amdgcn_mfma_f32_16x16x32_bf16(a0, whi[Tg][0], biasv[Tg], 0, 0, 0);
    #pragma unroll
    for (int Tg = 0; Tg < 4; ++Tg)
        alo[Tg] = __builtin_amdgcn_mfma_f32_16x16x32_bf16(a0, wlo[Tg][0], z, 0, 0, 0);
    #pragma unroll
    for (int Tg = 0; Tg < 4; ++Tg)
        ahi[Tg] = __builtin_amdgcn_mfma_f32_16x16x32_bf16(a1, whi[Tg][1], ahi[Tg], 0, 0, 0);
    #pragma unroll
    for (int Tg = 0; Tg < 4; ++Tg)
        alo[Tg] = __builtin_amdgcn_mfma_f32_16x16x32_bf16(a1, wlo[Tg][1], alo[Tg], 0, 0, 0);
    #pragma unroll
    for (int Tg = 0; Tg < 4; ++Tg)
        ahi[Tg] = __builtin_amdgcn_mfma_f32_16x16x32_bf16(a2, whi[Tg][2], ahi[Tg], 0, 0, 0);
    #pragma unroll
    for (int Tg = 0; Tg < 4; ++Tg)
        alo[Tg] = __builtin_amdgcn_mfma_f32_16x16x32_bf16(a2, wlo[Tg][2], alo[Tg], 0, 0, 0);

    // C/D layout: col = lane&15 (gate col), row m = quad*4 + r (batch).
    #pragma unroll
    for (int r = 0; r < 4; ++r) {
        float iv = ahi[0][r] + alo[0][r];
        float fv = ahi[1][r] + alo[1][r];
        float gv = ahi[2][r] + alo[2][r];
        float ov = ahi[3][r] + alo[3][r];
        float cn = sigf(fv) * cst[r] + sigf(iv) * tanh_f(gv);
        float hn = sigf(ov) * tanh_f(cn);
        cst[r] = cn;
        nxt[(quad * 4 + r) * ROWS + u] = f2bf(hn);
    }
}

__global__ __launch_bounds__(256, 1)
void seq2seq_mfma(const float* __restrict__ x_seq,
                  const float* __restrict__ eWih, const float* __restrict__ eWhh,
                  const float* __restrict__ ebih, const float* __restrict__ ebhh,
                  const float* __restrict__ dWih, const float* __restrict__ dWhh,
                  const float* __restrict__ dbih, const float* __restrict__ dbhh,
                  const float* __restrict__ fcW,  const float* __restrict__ fcb,
                  float* __restrict__ out)
{
    __shared__ __align__(16) short xchunk[CH * XR];      // 34816 B; predbuf alias in decoder
    __shared__ __align__(16) short Abuf[2][MB * ROWS];   // 4608 B
    __shared__ float fcWT[Hh * 9 + 8];                   // [u][f] stride 9 (bank-spread)
    __shared__ float sfcb[Ff];
    __shared__ __align__(16) short xdec[MB * Ff];        // decoder feedback x (bf16)

    const int tid  = threadIdx.x;
    const int wv   = tid >> 6;
    const int lane = tid & 63;
    const int quad = lane >> 4;
    const int col  = lane & 15;
    const int u    = wv * 16 + col;
    const int b0   = blockIdx.x * MB;

    short8 whi[4][3], wlo[4][3];
    load_wfrags(eWhh, eWih, wv, quad, col, whi, wlo);
    f32x4 biasv[4];
    #pragma unroll
    for (int Tg = 0; Tg < 4; ++Tg) {
        int g = Tg * 64 + u;
        float bv = ebih[g] + ebhh[g];
        biasv[Tg] = (f32x4){bv, bv, bv, bv};
    }

    // init: zero both h buffers, stage fc weights (transposed) + bias
    { int* Z = (int*)Abuf; for (int i = tid; i < MB * ROWS; i += 256) Z[i] = 0; }
    for (int i = tid; i < Ff * Hh; i += 256) { int f = i >> 6, uu = i & 63; fcWT[uu * 9 + f] = fcW[i]; }
    if (tid < Ff) sfcb[tid] = fcb[tid];
    __syncthreads();

    f32x4 cst = {0.f, 0.f, 0.f, 0.f};
    int curb = 0;

    // ================= encoder: 512 steps, global-free inner loop =================
    for (int t = 0; t < Tt; ++t) {
        if ((t & (CH - 1)) == 0) {
            // restage x[t .. t+CH) -> xchunk (fp32 global -> bf16 LDS), 4x per kernel
            for (int q = tid; q < MB * CH * 2; q += 256) {   // 4096 float4s
                int b  = q >> 8;                // 256 float4 per batch-chunk
                int r  = q & 255;
                int tt = r >> 1;
                int f4 = (r & 1) * 4;
                const float* src = x_seq + ((size_t)(b0 + b) * Tt + (t + tt)) * Ff + f4;
                float x0 = src[0], x1 = src[1], x2 = src[2], x3 = src[3];
                short4v s = {f2bf(x0), f2bf(x1), f2bf(x2), f2bf(x3)};
                *(short4v*)(&xchunk[tt * XR + b * 8 + f4]) = s;
            }
            __syncthreads();
        }
        lstm_step(Abuf[curb], Abuf[curb ^ 1], xchunk + (t & (CH - 1)) * XR,
                  whi, wlo, biasv, cst, quad, col, u);
        __syncthreads();
        curb ^= 1;
    }

    // ================= decoder setup =================
    load_wfrags(dWhh, dWih, wv, quad, col, whi, wlo);
    #pragma unroll
    for (int Tg = 0; Tg < 4; ++Tg) {
        int g = Tg * 64 + u;
        float bv = dbih[g] + dbhh[g];
        biasv[Tg] = (f32x4){bv, bv, bv, bv};
    }
    // x(dec,0) = x_seq[:, T-1] = last row of final chunk (row CH-1 survives predbuf alias)
    if (tid < MB * Ff) xdec[tid] = xchunk[(CH - 1) * XR + tid];
    __syncthreads();

    float* predbuf = (float*)xchunk;   // 32 KB, overlays dead xchunk rows 0..124

    // ================= decoder: 64 steps, fc + feedback, no global ops =================
    for (int p = 0; p < Pp; ++p) {
        lstm_step(Abuf[curb], Abuf[curb ^ 1], xdec, whi, wlo, biasv, cst, quad, col, u);
        __syncthreads();
        const short* hb = Abuf[curb ^ 1];
        if (tid < MB * Ff) {
            int b = tid >> 3, f = tid & 7;
            const short* hr = hb + b * ROWS;     // broadcast reads (8 lanes share row)
            float s = sfcb[f];
            #pragma unroll
            for (int ch = 0; ch < 8; ++ch) {
                short8 hh = *(const short8*)(hr + ch * 8);
                #pragma unroll
                for (int j = 0; j < 8; ++j)
                    s += bf2f_s(hh[j]) * fcWT[(ch * 8 + j) * 9 + f];
            }
            predbuf[b * (Pp * Ff) + p * Ff + f] = s;
            xdec[tid] = f2bf(s);
        }
        __syncthreads();
        curb ^= 1;
    }

    // ================= flush preds: LDS -> global, coalesced float4 =================
    {
        f32x4* out4 = (f32x4*)out + (size_t)b0 * (Pp * Ff / 4);
        const f32x4* pb4 = (const f32x4*)predbuf;
        for (int i = tid; i < MB * Pp * Ff / 4; i += 256)
            out4[i] = pb4[i];
    }
}

extern "C" void kernel_launch(void* const* d_in, const int* in_sizes, int n_in,
                              void* d_out, int out_size, void* d_ws, size_t ws_size,
                              hipStream_t stream) {
    (void)in_sizes; (void)n_in; (void)d_ws; (void)ws_size; (void)out_size;
    hipLaunchKernelGGL(seq2seq_mfma, dim3(NBLK), dim3(256), 0, stream,
                       (const float*)d_in[0],
                       (const float*)d_in[1], (const float*)d_in[2],
                       (const float*)d_in[3], (const float*)d_in[4],
                       (const float*)d_in[5], (const float*)d_in[6],
                       (const float*)d_in[7], (const float*)d_in[8],
                       (const float*)d_in[9], (const float*)d_in[10],
                       (float*)d_out);
}

// Round 5
// 363.163 us; speedup vs baseline: 2.0201x; 2.0201x over previous
//
#include <hip/hip_runtime.h>

// Seq2SeqLSTM: H=64, F=8, T=512, P=64, B=1024, fp32 in/out.
// R5: MB=4 over 256 blocks (all CUs). Batch b lives in A-row 4b, so the
// 16x16x32 C/D layout (row = quad*4+r) puts batch q's gates directly in
// acc[Tg][0] of quad-q lanes: zero cross-lane redistribution, 1 cell/lane,
// c-state in a scalar register, 1 barrier/step. Full x sequence in LDS (bf16).
// Weights pre-scaled by log2e (2*log2e for g-gate) -> raw v_exp/v_rcp cells.

#define Hh 64
#define Ff 8
#define Tt 512
#define Pp 64
#define BATCH 1024
#define MB 4
#define NBLK (BATCH / MB)   // 256 blocks
#define ROWS 72             // shorts per A row (64 + 8 pad) = 144 B (16B-aligned)
#define XSTRIDE 32          // shorts per x step-row: 4 batches * 8

typedef __attribute__((ext_vector_type(8))) short short8;
typedef __attribute__((ext_vector_type(4))) short short4v;
typedef __attribute__((ext_vector_type(4))) float f32x4;

#define LOG2E 1.44269504088896340736f

__device__ __forceinline__ short f2bf(float x) {           // fp32 -> bf16 (RNE)
    unsigned u = __float_as_uint(x);
    u += 0x7fffu + ((u >> 16) & 1u);
    return (short)(u >> 16);
}
__device__ __forceinline__ float bf2f_s(short s) {
    return __uint_as_float(((unsigned)(unsigned short)s) << 16);
}
// sigmoid with acc pre-scaled by log2e: sig = rcp(1 + exp2(-acc))
__device__ __forceinline__ float sig_pre(float acc) {
    return __builtin_amdgcn_rcpf(1.f + __builtin_amdgcn_exp2f(-acc));
}
// tanh with acc pre-scaled by 2*log2e: tanh = 1 - 2*rcp(exp2(acc) + 1)
__device__ __forceinline__ float tanh_pre(float acc) {
    return 1.f - 2.f * __builtin_amdgcn_rcpf(1.f + __builtin_amdgcn_exp2f(acc));
}

// B-fragments (weights): 4 gate tiles x 3 K-chunks, hi+lo bf16 split of the
// log2e-scaled weights. B layout (16x16x32): lane holds B[k=kc*32+quad*8+j][col].
// k 0..63 -> Whh[g][k]; k 64..71 -> Wih[g][k-64] (quad 0); else 0.
__device__ __forceinline__ void load_wfrags(
    const float* __restrict__ Whh, const float* __restrict__ Wih,
    int wv, int q, int col, short8 whi[4][3], short8 wlo[4][3])
{
    #pragma unroll
    for (int Tg = 0; Tg < 4; ++Tg) {
        int g = Tg * 64 + wv * 16 + col;
        float sc = (Tg == 2) ? (2.f * LOG2E) : LOG2E;
        const float* r0 = Whh + g * 64 + q * 8;
        const float* r1 = r0 + 32;
        #pragma unroll
        for (int j = 0; j < 8; ++j) {
            float v0 = r0[j] * sc;
            short h0 = f2bf(v0);
            whi[Tg][0][j] = h0;
            wlo[Tg][0][j] = f2bf(v0 - bf2f_s(h0));
            float v1 = r1[j] * sc;
            short h1 = f2bf(v1);
            whi[Tg][1][j] = h1;
            wlo[Tg][1][j] = f2bf(v1 - bf2f_s(h1));
            float v2 = (q == 0) ? (Wih[g * 8 + j] * sc) : 0.f;
            short h2 = f2bf(v2);
            whi[Tg][2][j] = h2;
            wlo[Tg][2][j] = f2bf(v2 - bf2f_s(h2));
        }
    }
}

// One step: 24 MFMA (8 independent depth-3 chains) + in-lane cell update.
// Returns h_new for this lane's cell; updates c in place.
__device__ __forceinline__ float lstm_cell(
    short8 a0, short8 a1, short8 a2,
    const short8 whi[4][3], const short8 wlo[4][3],
    const f32x4 biasv[4], float& c)
{
    f32x4 z = {0.f, 0.f, 0.f, 0.f};
    f32x4 hi[4], lo[4];
    #pragma unroll
    for (int Tg = 0; Tg < 4; ++Tg) {
        hi[Tg] = __builtin_amdgcn_mfma_f32_16x16x32_bf16(a0, whi[Tg][0], biasv[Tg], 0, 0, 0);
        lo[Tg] = __builtin_amdgcn_mfma_f32_16x16x32_bf16(a0, wlo[Tg][0], z, 0, 0, 0);
    }
    #pragma unroll
    for (int Tg = 0; Tg < 4; ++Tg) {
        hi[Tg] = __builtin_amdgcn_mfma_f32_16x16x32_bf16(a1, whi[Tg][1], hi[Tg], 0, 0, 0);
        lo[Tg] = __builtin_amdgcn_mfma_f32_16x16x32_bf16(a1, wlo[Tg][1], lo[Tg], 0, 0, 0);
    }
    #pragma unroll
    for (int Tg = 0; Tg < 4; ++Tg) {
        hi[Tg] = __builtin_amdgcn_mfma_f32_16x16x32_bf16(a2, whi[Tg][2], hi[Tg], 0, 0, 0);
        lo[Tg] = __builtin_amdgcn_mfma_f32_16x16x32_bf16(a2, wlo[Tg][2], lo[Tg], 0, 0, 0);
    }
    // This lane's cell gates live in component 0 (D row 4q = batch q).
    float gi = hi[0][0] + lo[0][0];
    float gf = hi[1][0] + lo[1][0];
    float gg = hi[2][0] + lo[2][0];
    float go = hi[3][0] + lo[3][0];
    float cn = sig_pre(gf) * c + sig_pre(gi) * tanh_pre(gg);
    float hn = sig_pre(go) * tanh_pre(2.f * LOG2E * cn);
    c = cn;
    return hn;
}

__global__ __launch_bounds__(256, 1)
void seq2seq_v5(const float* __restrict__ x_seq,
                const float* __restrict__ eWih, const float* __restrict__ eWhh,
                const float* __restrict__ ebih, const float* __restrict__ ebhh,
                const float* __restrict__ dWih, const float* __restrict__ dWhh,
                const float* __restrict__ dbih, const float* __restrict__ dbhh,
                const float* __restrict__ fcW,  const float* __restrict__ fcb,
                float* __restrict__ out)
{
    __shared__ __align__(16) short xs[Tt * XSTRIDE];     // 32 KB; predbuf alias in decoder
    __shared__ __align__(16) short Abuf[2][16 * ROWS];   // 4.6 KB, rows 0,4,8,12 = batches
    __shared__ float fcWT[Hh * 9 + 8];                   // [u][f] stride 9 (bank-spread)
    __shared__ float sfcb[Ff];
    __shared__ __align__(16) short xdec[MB * Ff];        // decoder feedback x (bf16)

    const int tid = threadIdx.x;
    const int wv  = tid >> 6;
    const int lane = tid & 63;
    const int q   = lane >> 4;
    const int col = lane & 15;
    const int u   = wv * 16 + col;       // unit owned by this lane
    const int b0  = blockIdx.x * MB;

    short8 whi[4][3], wlo[4][3];
    load_wfrags(eWhh, eWih, wv, q, col, whi, wlo);
    f32x4 biasv[4];
    #pragma unroll
    for (int Tg = 0; Tg < 4; ++Tg) {
        int g = Tg * 64 + u;
        float sc = (Tg == 2) ? (2.f * LOG2E) : LOG2E;
        float bv = (ebih[g] + ebhh[g]) * sc;
        biasv[Tg] = (f32x4){bv, bv, bv, bv};
    }

    // init: zero both A buffers (h=0 rows + zero filler rows), fc weights, x stage
    { int* Z = (int*)Abuf; for (int i = tid; i < 16 * ROWS; i += 256) Z[i] = 0; }
    for (int i = tid; i < Ff * Hh; i += 256) { int f = i >> 6, uu = i & 63; fcWT[uu * 9 + f] = fcW[i]; }
    if (tid < Ff) sfcb[tid] = fcb[tid];
    // stage full x sequence: 4 batches x 512 steps x 8 (fp32 -> bf16), 16 float4/thread
    for (int i = tid; i < MB * Tt * 2; i += 256) {       // 4096 float4s
        int b   = i >> 10;               // 1024 float4 per batch
        int rem = i & 1023;
        int t   = rem >> 1;
        int f4  = (rem & 1) * 4;
        const float* src = x_seq + ((size_t)(b0 + b) * Tt + t) * Ff + f4;
        float x0 = src[0], x1 = src[1], x2 = src[2], x3 = src[3];
        short4v s = {f2bf(x0), f2bf(x1), f2bf(x2), f2bf(x3)};
        *(short4v*)(&xs[t * XSTRIDE + b * 8 + f4]) = s;
    }
    __syncthreads();

    float c = 0.f;
    int curb = 0;

    // ================= encoder: 512 steps, 1 barrier each, global-free =================
    for (int t = 0; t < Tt; ++t) {
        const short* cur = Abuf[curb];
        short*       nxt = Abuf[curb ^ 1];
        const short* arow = cur + col * ROWS;
        short8 a0 = *(const short8*)(arow + q * 8);          // k  0..31 (h)
        short8 a1 = *(const short8*)(arow + 32 + q * 8);     // k 32..63 (h)
        short8 a2 = {0, 0, 0, 0, 0, 0, 0, 0};                // k 64..95 (x | zeros)
        if (q == 0 && (col & 3) == 0)
            a2 = *(const short8*)(xs + t * XSTRIDE + (col >> 2) * 8);
        float hn = lstm_cell(a0, a1, a2, whi, wlo, biasv, c);
        nxt[4 * q * ROWS + u] = f2bf(hn);                    // batch q -> A-row 4q
        __syncthreads();
        curb ^= 1;
    }

    // ================= decoder setup =================
    load_wfrags(dWhh, dWih, wv, q, col, whi, wlo);
    #pragma unroll
    for (int Tg = 0; Tg < 4; ++Tg) {
        int g = Tg * 64 + u;
        float sc = (Tg == 2) ? (2.f * LOG2E) : LOG2E;
        float bv = (dbih[g] + dbhh[g]) * sc;
        biasv[Tg] = (f32x4){bv, bv, bv, bv};
    }
    if (tid < MB * Ff) xdec[tid] = xs[(Tt - 1) * XSTRIDE + tid];   // x_dec(0) = x[:, T-1]
    __syncthreads();

    float* predbuf = (float*)xs;   // 8 KB alias over dead xs rows 0..255

    // ================= decoder: 64 steps, fc + feedback, global-free =================
    for (int p = 0; p < Pp; ++p) {
        const short* cur = Abuf[curb];
        short*       nxt = Abuf[curb ^ 1];
        const short* arow = cur + col * ROWS;
        short8 a0 = *(const short8*)(arow + q * 8);
        short8 a1 = *(const short8*)(arow + 32 + q * 8);
        short8 a2 = {0, 0, 0, 0, 0, 0, 0, 0};
        if (q == 0 && (col & 3) == 0)
            a2 = *(const short8*)(xdec + (col >> 2) * 8);
        float hn = lstm_cell(a0, a1, a2, whi, wlo, biasv, c);
        nxt[4 * q * ROWS + u] = f2bf(hn);
        __syncthreads();
        // fc head on 32 threads: pred = h_new @ fcW^T + fcb
        if (tid < MB * Ff) {
            int b = tid >> 3, f = tid & 7;
            const short* hr = nxt + (4 * b) * ROWS;          // batch b = A-row 4b
            float s = sfcb[f];
            #pragma unroll
            for (int ch = 0; ch < 8; ++ch) {
                short8 hh = *(const short8*)(hr + ch * 8);
                #pragma unroll
                for (int j = 0; j < 8; ++j)
                    s += bf2f_s(hh[j]) * fcWT[(ch * 8 + j) * 9 + f];
            }
            predbuf[b * (Pp * Ff) + p * Ff + f] = s;
            xdec[tid] = f2bf(s);
        }
        __syncthreads();
        curb ^= 1;
    }

    // ================= flush preds: LDS -> global, coalesced float4 =================
    {
        f32x4* out4 = (f32x4*)out + (size_t)b0 * (Pp * Ff / 4);
        const f32x4* pb4 = (const f32x4*)predbuf;
        for (int i = tid; i < MB * Pp * Ff / 4; i += 256)
            out4[i] = pb4[i];
    }
}

extern "C" void kernel_launch(void* const* d_in, const int* in_sizes, int n_in,
                              void* d_out, int out_size, void* d_ws, size_t ws_size,
                              hipStream_t stream) {
    (void)in_sizes; (void)n_in; (void)d_ws; (void)ws_size; (void)out_size;
    hipLaunchKernelGGL(seq2seq_v5, dim3(NBLK), dim3(256), 0, stream,
                       (const float*)d_in[0],
                       (const float*)d_in[1], (const float*)d_in[2],
                       (const float*)d_in[3], (const float*)d_in[4],
                       (const float*)d_in[5], (const float*)d_in[6],
                       (const float*)d_in[7], (const float*)d_in[8],
                       (const float*)d_in[9], (const float*)d_in[10],
                       (float*)d_out);
}

// Round 6
// 274.118 us; speedup vs baseline: 2.6764x; 1.3248x over previous
//
#include <hip/hip_runtime.h>

// Seq2SeqLSTM: H=64, F=8, T=512, P=64, B=1024, fp32 in/out.
// R6: fp16 matmul path (fp16 weights+h+x beat bf16 hi/lo: 2^-11 vs 2^-8 rel,
// and h-quant error dominated R5's absmax). 12 MFMA/step (was 24), depth<=2.
// Unconditional a2 loads (zero B rows k=72..95 make garbage lanes harmless),
// x prefetched 1 step ahead, c kept pre-scaled by 2*log2e, encoder unroll x2.
// MB=4 over 256 blocks; lane (q,col) owns cell (batch q, unit wv*16+col);
// batch b lives in A-row 4b so C/D row=q*4 puts gates in acc[.][0] in-lane.

#define Hh 64
#define Ff 8
#define Tt 512
#define Pp 64
#define BATCH 1024
#define MB 4
#define NBLK (BATCH / MB)   // 256 blocks
#define ROWS 72             // halves per A row (64 + 8 pad) = 144 B (16B-aligned)
#define XSTRIDE 32          // halves per x step-row: 4 batches * 8

typedef __attribute__((ext_vector_type(8))) _Float16 half8;
typedef __attribute__((ext_vector_type(4))) _Float16 half4;
typedef __attribute__((ext_vector_type(4))) float f32x4;

#define LOG2E  1.44269504088896340736f
#define K2LOG2 2.88538008177792681472f   // 2*log2e

__device__ __forceinline__ float sig_pre(float a) {   // a pre-scaled by log2e
    return __builtin_amdgcn_rcpf(1.f + __builtin_amdgcn_exp2f(-a));
}
__device__ __forceinline__ float tanh_pre(float a) {  // a pre-scaled by 2*log2e
    return 1.f - 2.f * __builtin_amdgcn_rcpf(1.f + __builtin_amdgcn_exp2f(a));
}

// B-fragments: 4 gate tiles x 3 K-chunks, fp16, log2e-pre-scaled.
// B layout (16x16x32): lane holds B[k = kc*32 + q*8 + j][n = col].
// k 0..63 -> Whh[g][k]; k 64..71 -> Wih[g][k-64] (q==0); k 72..95 -> 0.
__device__ __forceinline__ void load_wfrags(
    const float* __restrict__ Whh, const float* __restrict__ Wih,
    int wv, int q, int col, half8 w[4][3])
{
    #pragma unroll
    for (int Tg = 0; Tg < 4; ++Tg) {
        int g = Tg * 64 + wv * 16 + col;
        float sc = (Tg == 2) ? K2LOG2 : LOG2E;
        const float* r0 = Whh + g * 64 + q * 8;
        #pragma unroll
        for (int j = 0; j < 8; ++j) {
            w[Tg][0][j] = (_Float16)(r0[j] * sc);
            w[Tg][1][j] = (_Float16)(r0[32 + j] * sc);
            w[Tg][2][j] = (q == 0) ? (_Float16)(Wih[g * 8 + j] * sc) : (_Float16)0.f;
        }
    }
}

// One step: 12 MFMA (4 depth-2 chains + 4 indep) + in-lane cell update.
// cS = 2*log2e * c (pre-scaled). Returns h_new (fp32).
__device__ __forceinline__ float lstm_cell(
    half8 a0, half8 a1, half8 ax,
    const half8 w[4][3], const f32x4 biasv[4], float& cS)
{
    f32x4 z = {0.f, 0.f, 0.f, 0.f};
    f32x4 Q0, Q1, Q2, Q3, P0, P1, P2, P3;
    Q2 = __builtin_amdgcn_mfma_f32_16x16x32_f16(a0, w[2][0], biasv[2], 0, 0, 0);
    Q0 = __builtin_amdgcn_mfma_f32_16x16x32_f16(a0, w[0][0], biasv[0], 0, 0, 0);
    Q1 = __builtin_amdgcn_mfma_f32_16x16x32_f16(a0, w[1][0], biasv[1], 0, 0, 0);
    Q3 = __builtin_amdgcn_mfma_f32_16x16x32_f16(a0, w[3][0], biasv[3], 0, 0, 0);
    P2 = __builtin_amdgcn_mfma_f32_16x16x32_f16(ax, w[2][2], z, 0, 0, 0);
    P0 = __builtin_amdgcn_mfma_f32_16x16x32_f16(ax, w[0][2], z, 0, 0, 0);
    P1 = __builtin_amdgcn_mfma_f32_16x16x32_f16(ax, w[1][2], z, 0, 0, 0);
    P3 = __builtin_amdgcn_mfma_f32_16x16x32_f16(ax, w[3][2], z, 0, 0, 0);
    Q2 = __builtin_amdgcn_mfma_f32_16x16x32_f16(a1, w[2][1], Q2, 0, 0, 0);
    Q0 = __builtin_amdgcn_mfma_f32_16x16x32_f16(a1, w[0][1], Q0, 0, 0, 0);
    Q1 = __builtin_amdgcn_mfma_f32_16x16x32_f16(a1, w[1][1], Q1, 0, 0, 0);
    Q3 = __builtin_amdgcn_mfma_f32_16x16x32_f16(a1, w[3][1], Q3, 0, 0, 0);

    float gg = Q2[0] + P2[0];
    float gi = Q0[0] + P0[0];
    float gf = Q1[0] + P1[0];
    float go = Q3[0] + P3[0];
    float tg = tanh_pre(gg);          // gg pre-scaled by 2*log2e
    float si = sig_pre(gi);
    float sf = sig_pre(gf);
    float so = sig_pre(go);
    cS = sf * cS + si * (K2LOG2 * tg);
    float th = tanh_pre(cS);          // cS already 2*log2e-scaled
    return so * th;
}

__global__ __launch_bounds__(256, 1)
void seq2seq_v6(const float* __restrict__ x_seq,
                const float* __restrict__ eWih, const float* __restrict__ eWhh,
                const float* __restrict__ ebih, const float* __restrict__ ebhh,
                const float* __restrict__ dWih, const float* __restrict__ dWhh,
                const float* __restrict__ dbih, const float* __restrict__ dbhh,
                const float* __restrict__ fcW,  const float* __restrict__ fcb,
                float* __restrict__ out)
{
    __shared__ __align__(16) _Float16 xs[Tt * XSTRIDE];     // 32 KB; predbuf alias later
    __shared__ __align__(16) _Float16 A0[16 * ROWS];        // 2.3 KB each
    __shared__ __align__(16) _Float16 A1[16 * ROWS];
    __shared__ float fcWT[Hh * 9 + 8];
    __shared__ float sfcb[Ff];
    __shared__ __align__(16) _Float16 xdec[MB * Ff];

    const int tid  = threadIdx.x;
    const int wv   = tid >> 6;
    const int lane = tid & 63;
    const int q    = lane >> 4;
    const int col  = lane & 15;
    const int u    = wv * 16 + col;
    const int b0   = blockIdx.x * MB;

    half8 w[4][3];
    load_wfrags(eWhh, eWih, wv, q, col, w);
    f32x4 biasv[4];
    #pragma unroll
    for (int Tg = 0; Tg < 4; ++Tg) {
        int g = Tg * 64 + u;
        float sc = (Tg == 2) ? K2LOG2 : LOG2E;
        float bv = (ebih[g] + ebhh[g]) * sc;
        biasv[Tg] = (f32x4){bv, bv, bv, bv};
    }

    // init: zero both A buffers, stage fc weights + x sequence (fp32 -> fp16)
    { int* Z0 = (int*)A0; int* Z1 = (int*)A1;
      for (int i = tid; i < 16 * ROWS / 2; i += 256) { Z0[i] = 0; Z1[i] = 0; } }
    for (int i = tid; i < Ff * Hh; i += 256) { int f = i >> 6, uu = i & 63; fcWT[uu * 9 + f] = fcW[i]; }
    if (tid < Ff) sfcb[tid] = fcb[tid];
    for (int i = tid; i < MB * Tt * 2; i += 256) {       // 4096 float4s
        int b   = i >> 10;
        int rem = i & 1023;
        int t   = rem >> 1;
        int f4  = (rem & 1) * 4;
        const float* src = x_seq + ((size_t)(b0 + b) * Tt + t) * Ff + f4;
        half4 s = { (_Float16)src[0], (_Float16)src[1], (_Float16)src[2], (_Float16)src[3] };
        *(half4*)(&xs[t * XSTRIDE + b * 8 + f4]) = s;
    }
    __syncthreads();

    // per-lane hoisted pointers
    const _Float16* ar0 = A0 + col * ROWS + q * 8;   // a0 read, buffer A0
    const _Float16* ar1 = A1 + col * ROWS + q * 8;
    _Float16* hw0 = A0 + 4 * q * ROWS + u;           // h write, buffer A0
    _Float16* hw1 = A1 + 4 * q * ROWS + u;
    const _Float16* xp = xs + (col >> 2) * 8;        // all lanes read (4-way bcast)

    float cS = 0.f;
    half8 xa = *(const half8*)(xp);                  // x(t=0)

    // ============ encoder: 512 steps, unrolled x2, 1 barrier/step ============
    for (int t = 0; t < Tt; t += 2) {
        // step t: read A0, write A1
        half8 xan = *(const half8*)(xp + (t + 1) * XSTRIDE);     // prefetch t+1
        {
            half8 a0 = *(const half8*)(ar0);
            half8 a1 = *(const half8*)(ar0 + 32);
            float hn = lstm_cell(a0, a1, xa, w, biasv, cS);
            *hw1 = (_Float16)hn;
        }
        __syncthreads();
        // step t+1: read A1, write A0
        half8 xa2 = *(const half8*)(xp + ((t + 2 < Tt) ? (t + 2) : 0) * XSTRIDE);
        {
            half8 a0 = *(const half8*)(ar1);
            half8 a1 = *(const half8*)(ar1 + 32);
            float hn = lstm_cell(a0, a1, xan, w, biasv, cS);
            *hw0 = (_Float16)hn;
        }
        __syncthreads();
        xa = xa2;
    }

    // ================= decoder setup =================
    load_wfrags(dWhh, dWih, wv, q, col, w);
    #pragma unroll
    for (int Tg = 0; Tg < 4; ++Tg) {
        int g = Tg * 64 + u;
        float sc = (Tg == 2) ? K2LOG2 : LOG2E;
        float bv = (dbih[g] + dbhh[g]) * sc;
        biasv[Tg] = (f32x4){bv, bv, bv, bv};
    }
    if (tid < MB * Ff) xdec[tid] = xs[(Tt - 1) * XSTRIDE + tid];   // x_dec(0)=x[:,T-1]
    __syncthreads();

    float* predbuf = (float*)xs;                     // 8 KB alias over dead xs
    const _Float16* xdp = xdec + (col >> 2) * 8;

    // ============ decoder: 64 steps (A0 -> A1 -> A0 ...), fc + feedback ============
    for (int p = 0; p < Pp; ++p) {
        const _Float16* ar = (p & 1) ? ar1 : ar0;
        _Float16*       hw = (p & 1) ? hw0 : hw1;
        const _Float16* hb = (p & 1) ? A0  : A1;     // buffer written this step
        half8 a0 = *(const half8*)(ar);
        half8 a1 = *(const half8*)(ar + 32);
        half8 ax = *(const half8*)(xdp);
        float hn = lstm_cell(a0, a1, ax, w, biasv, cS);
        *hw = (_Float16)hn;
        __syncthreads();
        if (tid < MB * Ff) {
            int b = tid >> 3, f = tid & 7;
            const _Float16* hr = hb + (4 * b) * ROWS;
            float s = sfcb[f];
            #pragma unroll
            for (int ch = 0; ch < 8; ++ch) {
                half8 hh = *(const half8*)(hr + ch * 8);
                #pragma unroll
                for (int j = 0; j < 8; ++j)
                    s += (float)hh[j] * fcWT[(ch * 8 + j) * 9 + f];
            }
            predbuf[b * (Pp * Ff) + p * Ff + f] = s;
            xdec[tid] = (_Float16)s;
        }
        __syncthreads();
    }

    // ================= flush preds: LDS -> global, coalesced float4 =================
    {
        f32x4* out4 = (f32x4*)out + (size_t)b0 * (Pp * Ff / 4);
        const f32x4* pb4 = (const f32x4*)predbuf;
        for (int i = tid; i < MB * Pp * Ff / 4; i += 256)
            out4[i] = pb4[i];
    }
}

extern "C" void kernel_launch(void* const* d_in, const int* in_sizes, int n_in,
                              void* d_out, int out_size, void* d_ws, size_t ws_size,
                              hipStream_t stream) {
    (void)in_sizes; (void)n_in; (void)d_ws; (void)ws_size; (void)out_size;
    hipLaunchKernelGGL(seq2seq_v6, dim3(NBLK), dim3(256), 0, stream,
                       (const float*)d_in[0],
                       (const float*)d_in[1], (const float*)d_in[2],
                       (const float*)d_in[3], (const float*)d_in[4],
                       (const float*)d_in[5], (const float*)d_in[6],
                       (const float*)d_in[7], (const float*)d_in[8],
                       (const float*)d_in[9], (const float*)d_in[10],
                       (float*)d_out);
}

// Round 7
// 258.567 us; speedup vs baseline: 2.8373x; 1.0601x over previous
//
#include <hip/hip_runtime.h>

// Seq2SeqLSTM: H=64, F=8, T=512, P=64, B=1024, fp32 in/out.
// R7: (1) x-MFMAs (P-chain) computed one step ahead in the barrier shadow ->
// post-barrier CP is 8 MFMAs (4 chains, depth 2, C chained through P+bias);
// (2) A-row swizzle base(m)=m*72+(m&3)*16 makes the all-lanes A-read 2-way
// bank-clean (writers at rows 4b unaffected; junk rows land in unused D rows);
// (3) pointer-increment addressing, barrier-at-top loop.
// MB=4 over 256 blocks; lane (q,col) owns cell (batch q, unit wv*16+col);
// batch b at A-row 4b so C/D row=4q+0 puts the lane's gates in acc[.][0].

#define Hh 64
#define Ff 8
#define Tt 512
#define Pp 64
#define BATCH 1024
#define MB 4
#define NBLK (BATCH / MB)   // 256 blocks
#define ROWS 72             // halves per A row (64 + 8 pad)
#define ABUF (16 * ROWS + 64)
#define XSTRIDE 32          // halves per x step-row: 4 batches * 8

typedef __attribute__((ext_vector_type(8))) _Float16 half8;
typedef __attribute__((ext_vector_type(4))) _Float16 half4;
typedef __attribute__((ext_vector_type(4))) float f32x4;

#define LOG2E  1.44269504088896340736f
#define K2LOG2 2.88538008177792681472f   // 2*log2e

__device__ __forceinline__ float sig_pre(float a) {   // a pre-scaled by log2e
    return __builtin_amdgcn_rcpf(1.f + __builtin_amdgcn_exp2f(-a));
}
__device__ __forceinline__ float tanh_pre(float a) {  // a pre-scaled by 2*log2e
    return 1.f - 2.f * __builtin_amdgcn_rcpf(1.f + __builtin_amdgcn_exp2f(a));
}
// A-row swizzle (halves): rows 4b (writers) keep offset 0; junk rows spread banks.
__device__ __forceinline__ int arow_base(int m) { return m * ROWS + (m & 3) * 16; }

// B-fragments: 4 gate tiles, fp16, log2e-pre-scaled (2*log2e for g-gate).
// B layout (16x16x32): lane holds B[k = kc*32 + q*8 + j][n = col].
// w0: k 0..31 (h), w1: k 32..63 (h), wx: k 64..95 (x in 64..71, else 0).
__device__ __forceinline__ void load_wfrags(
    const float* __restrict__ Whh, const float* __restrict__ Wih,
    int wv, int q, int col, half8 w0[4], half8 w1[4], half8 wx[4])
{
    #pragma unroll
    for (int Tg = 0; Tg < 4; ++Tg) {
        int g = Tg * 64 + wv * 16 + col;
        float sc = (Tg == 2) ? K2LOG2 : LOG2E;
        const float* r0 = Whh + g * 64 + q * 8;
        #pragma unroll
        for (int j = 0; j < 8; ++j) {
            w0[Tg][j] = (_Float16)(r0[j] * sc);
            w1[Tg][j] = (_Float16)(r0[32 + j] * sc);
            wx[Tg][j] = (q == 0) ? (_Float16)(Wih[g * 8 + j] * sc) : (_Float16)0.f;
        }
    }
}

// Shadow phase: P[Tg] = x-contribution + bias (C-init), off the critical path.
__device__ __forceinline__ void pchain(half8 ax, const half8 wx[4],
                                       const f32x4 biasv[4], f32x4 P[4])
{
    #pragma unroll
    for (int Tg = 0; Tg < 4; ++Tg)
        P[Tg] = __builtin_amdgcn_mfma_f32_16x16x32_f16(ax, wx[Tg], biasv[Tg], 0, 0, 0);
}

// Critical path: 8 MFMA (4 chains depth 2) + cell update. Returns h_new.
__device__ __forceinline__ float qcell(half8 a0, half8 a1,
    const half8 w0[4], const half8 w1[4], const f32x4 P[4], float& cS)
{
    f32x4 Q[4];
    #pragma unroll
    for (int Tg = 0; Tg < 4; ++Tg)
        Q[Tg] = __builtin_amdgcn_mfma_f32_16x16x32_f16(a0, w0[Tg], P[Tg], 0, 0, 0);
    #pragma unroll
    for (int Tg = 0; Tg < 4; ++Tg)
        Q[Tg] = __builtin_amdgcn_mfma_f32_16x16x32_f16(a1, w1[Tg], Q[Tg], 0, 0, 0);
    float si = sig_pre(Q[0][0]);
    float sf = sig_pre(Q[1][0]);
    float tg = tanh_pre(Q[2][0]);
    float so = sig_pre(Q[3][0]);
    cS = sf * cS + si * (K2LOG2 * tg);
    return so * tanh_pre(cS);
}

__global__ __launch_bounds__(256, 1)
void seq2seq_v7(const float* __restrict__ x_seq,
                const float* __restrict__ eWih, const float* __restrict__ eWhh,
                const float* __restrict__ ebih, const float* __restrict__ ebhh,
                const float* __restrict__ dWih, const float* __restrict__ dWhh,
                const float* __restrict__ dbih, const float* __restrict__ dbhh,
                const float* __restrict__ fcW,  const float* __restrict__ fcb,
                float* __restrict__ out)
{
    __shared__ __align__(16) _Float16 xs[(Tt + 2) * XSTRIDE];  // 32.9 KB; predbuf alias later
    __shared__ __align__(16) _Float16 A0[ABUF];
    __shared__ __align__(16) _Float16 A1[ABUF];
    __shared__ float fcWT[Hh * 9 + 8];
    __shared__ float sfcb[Ff];
    __shared__ __align__(16) _Float16 xdec[MB * Ff];

    const int tid  = threadIdx.x;
    const int wv   = tid >> 6;
    const int lane = tid & 63;
    const int q    = lane >> 4;
    const int col  = lane & 15;
    const int u    = wv * 16 + col;
    const int b0   = blockIdx.x * MB;

    half8 w0[4], w1[4], wx[4];
    load_wfrags(eWhh, eWih, wv, q, col, w0, w1, wx);
    f32x4 biasv[4];
    #pragma unroll
    for (int Tg = 0; Tg < 4; ++Tg) {
        int g = Tg * 64 + u;
        float sc = (Tg == 2) ? K2LOG2 : LOG2E;
        float bv = (ebih[g] + ebhh[g]) * sc;
        biasv[Tg] = (f32x4){bv, bv, bv, bv};
    }

    // init: zero both A buffers, stage fc weights + x sequence (fp32 -> fp16)
    { int* Z0 = (int*)A0; int* Z1 = (int*)A1;
      for (int i = tid; i < ABUF / 2; i += 256) { Z0[i] = 0; Z1[i] = 0; } }
    for (int i = tid; i < Ff * Hh; i += 256) { int f = i >> 6, uu = i & 63; fcWT[uu * 9 + f] = fcW[i]; }
    if (tid < Ff) sfcb[tid] = fcb[tid];
    if (tid < 32) ((int*)xs)[Tt * 16 + tid] = 0;         // zero 2 pad rows
    for (int i = tid; i < MB * Tt * 2; i += 256) {       // 4096 float4s
        int b   = i >> 10;
        int rem = i & 1023;
        int t   = rem >> 1;
        int f4  = (rem & 1) * 4;
        const float* src = x_seq + ((size_t)(b0 + b) * Tt + t) * Ff + f4;
        half4 s = { (_Float16)src[0], (_Float16)src[1], (_Float16)src[2], (_Float16)src[3] };
        *(half4*)(&xs[t * XSTRIDE + b * 8 + f4]) = s;
    }
    __syncthreads();                                     // staging visible

    // per-lane hoisted pointers (swizzled A reads; writers at rows 4b, swizzle 0)
    const _Float16* arA = A0 + arow_base(col) + q * 8;
    const _Float16* arB = A1 + arow_base(col) + q * 8;
    _Float16* hwA = A0 + 4 * q * ROWS + u;
    _Float16* hwB = A1 + 4 * q * ROWS + u;
    const _Float16* xq = xs + (col >> 2) * 8;            // x walker (broadcast groups)

    float cS = 0.f;
    f32x4 P[4];
    {   half8 ax = *(const half8*)(xq);                  // x(0)
        pchain(ax, wx, biasv, P);                        // P for step 0
        xq += XSTRIDE; }

    // ============ encoder: 512 steps, barrier at top, P one step ahead ============
    for (int t = 0; t < Tt; t += 2) {
        __syncthreads();                                 // h(t) visible (bufA)
        {
            half8 ax = *(const half8*)(xq); xq += XSTRIDE;   // x(t+1), off-CP
            half8 a0 = *(const half8*)(arA);
            half8 a1 = *(const half8*)(arA + 32);
            float hn = qcell(a0, a1, w0, w1, P, cS);
            *hwB = (_Float16)hn;                         // h(t+1) -> bufB
            pchain(ax, wx, biasv, P);                    // P for t+1 (shadow)
        }
        __syncthreads();                                 // h(t+1) visible (bufB)
        {
            half8 ax = *(const half8*)(xq); xq += XSTRIDE;   // x(t+2) (pad rows at end)
            half8 a0 = *(const half8*)(arB);
            half8 a1 = *(const half8*)(arB + 32);
            float hn = qcell(a0, a1, w0, w1, P, cS);
            *hwA = (_Float16)hn;                         // h(t+2) -> bufA
            pchain(ax, wx, biasv, P);                    // P for t+2 (shadow)
        }
    }
    // after loop: h(512) in bufA (t=511 odd step wrote A); trailing P unused.

    // ================= decoder setup =================
    load_wfrags(dWhh, dWih, wv, q, col, w0, w1, wx);
    #pragma unroll
    for (int Tg = 0; Tg < 4; ++Tg) {
        int g = Tg * 64 + u;
        float sc = (Tg == 2) ? K2LOG2 : LOG2E;
        float bv = (dbih[g] + dbhh[g]) * sc;
        biasv[Tg] = (f32x4){bv, bv, bv, bv};
    }
    if (tid < MB * Ff) xdec[tid] = xs[(Tt - 1) * XSTRIDE + tid];   // x_dec(0)=x[:,T-1]
    __syncthreads();                                     // h(512) + xdec visible

    float* predbuf = (float*)xs;                         // 8 KB alias over dead xs
    const _Float16* xdp = xdec + (col >> 2) * 8;

    // ============ decoder: 64 steps (bufA -> bufB -> ...), fc + feedback ============
    for (int p = 0; p < Pp; ++p) {
        const _Float16* ar = (p & 1) ? arB : arA;
        _Float16*       hw = (p & 1) ? hwA : hwB;
        const _Float16* hb = (p & 1) ? A0  : A1;         // buffer written this step
        half8 ax = *(const half8*)(xdp);
        pchain(ax, wx, biasv, P);                        // on-CP in decoder (64 steps only)
        half8 a0 = *(const half8*)(ar);
        half8 a1 = *(const half8*)(ar + 32);
        float hn = qcell(a0, a1, w0, w1, P, cS);
        *hw = (_Float16)hn;
        __syncthreads();
        if (tid < MB * Ff) {
            int b = tid >> 3, f = tid & 7;
            const _Float16* hr = hb + (4 * b) * ROWS;
            float s = sfcb[f];
            #pragma unroll
            for (int ch = 0; ch < 8; ++ch) {
                half8 hh = *(const half8*)(hr + ch * 8);
                #pragma unroll
                for (int j = 0; j < 8; ++j)
                    s += (float)hh[j] * fcWT[(ch * 8 + j) * 9 + f];
            }
            predbuf[b * (Pp * Ff) + p * Ff + f] = s;
            xdec[tid] = (_Float16)s;
        }
        __syncthreads();
    }

    // ================= flush preds: LDS -> global, coalesced float4 =================
    {
        f32x4* out4 = (f32x4*)out + (size_t)b0 * (Pp * Ff / 4);
        const f32x4* pb4 = (const f32x4*)predbuf;
        for (int i = tid; i < MB * Pp * Ff / 4; i += 256)
            out4[i] = pb4[i];
    }
}

extern "C" void kernel_launch(void* const* d_in, const int* in_sizes, int n_in,
                              void* d_out, int out_size, void* d_ws, size_t ws_size,
                              hipStream_t stream) {
    (void)in_sizes; (void)n_in; (void)d_ws; (void)ws_size; (void)out_size;
    hipLaunchKernelGGL(seq2seq_v7, dim3(NBLK), dim3(256), 0, stream,
                       (const float*)d_in[0],
                       (const float*)d_in[1], (const float*)d_in[2],
                       (const float*)d_in[3], (const float*)d_in[4],
                       (const float*)d_in[5], (const float*)d_in[6],
                       (const float*)d_in[7], (const float*)d_in[8],
                       (const float*)d_in[9], (const float*)d_in[10],
                       (float*)d_out);
}